// Round 3
// baseline (144.047 us; speedup 1.0000x reference)
//
#include <hip/hip_runtime.h>

#define TT 2048
#define EMB 1024
#define NH 16
#define HD 64
#define CTX 250

typedef __attribute__((ext_vector_type(4))) float f32x4;
typedef __attribute__((ext_vector_type(8))) short s16x8;
typedef __attribute__((ext_vector_type(4))) short s16x4;

#define LDS_PTR(p) ((__attribute__((address_space(3))) void*)(p))
#define GLB_PTR(p) ((const __attribute__((address_space(1))) void*)(p))

__device__ __forceinline__ short f2bf(float f) {
  union { float f; unsigned u; } v; v.f = f;
  unsigned r = v.u + 0x7fffu + ((v.u >> 16) & 1u);
  return (short)(r >> 16);
}
__device__ __forceinline__ float bf2f(unsigned short u) {
  union { unsigned u; float f; } v; v.u = ((unsigned)u) << 16;
  return v.f;
}

__global__ void cvt_bf16x4(const float* __restrict__ in, short* __restrict__ out, int n4) {
  int i = blockIdx.x * blockDim.x + threadIdx.x;
  if (i >= n4) return;
  float4 v = reinterpret_cast<const float4*>(in)[i];
  s16x4 o; o[0] = f2bf(v.x); o[1] = f2bf(v.y); o[2] = f2bf(v.z); o[3] = f2bf(v.w);
  *reinterpret_cast<s16x4*>(out + i * 4) = o;
}

// C[M][N] = A[M][K] * W[N][K]^T  (bf16, MFMA 16x16x32, f32 accum)
// m97 structure: LDS staging via global_load_lds width-16, BK=32, 4 waves.
template<int BM, bool BF16OUT>
__global__ __launch_bounds__(256) void gemm_lds(const short* __restrict__ A,
                                                const short* __restrict__ W,
                                                void* __restrict__ Cv, int N, int K) {
  constexpr int BN = 128;
  constexpr int BK = 32;
  constexpr int MFR = BM / 32;
  __shared__ __align__(16) short As[BM * BK];
  __shared__ __align__(16) short Bs[BN * BK];
  const int lane = threadIdx.x & 63;
  const int wid  = threadIdx.x >> 6;
  const int lr = lane & 15, lg = lane >> 4;
  const int rblk = blockIdx.y * BM;
  const int cblk = blockIdx.x * BN;
  const int wrow = (wid >> 1) * (BM / 2);
  const int wcol = (wid & 1) * 64;
  const int srow = lane >> 2;
  const int scol = (lane & 3) * 8;
  f32x4 acc[MFR][4] = {};

  for (int kk = 0; kk < K; kk += BK) {
#pragma unroll
    for (int j = 0; j < BM / 64; j++) {
      int seg = wid * (BM / 64) + j;
      const short* g = A + (size_t)(rblk + seg * 16 + srow) * K + kk + scol;
      __builtin_amdgcn_global_load_lds(GLB_PTR(g), LDS_PTR(&As[seg * 512]), 16, 0, 0);
    }
#pragma unroll
    for (int j = 0; j < 2; j++) {
      int seg = wid * 2 + j;
      const short* g = W + (size_t)(cblk + seg * 16 + srow) * K + kk + scol;
      __builtin_amdgcn_global_load_lds(GLB_PTR(g), LDS_PTR(&Bs[seg * 512]), 16, 0, 0);
    }
    __syncthreads();
    s16x8 af[MFR], bfr[4];
#pragma unroll
    for (int m = 0; m < MFR; m++)
      af[m] = *reinterpret_cast<const s16x8*>(&As[(wrow + m * 16 + lr) * BK + lg * 8]);
#pragma unroll
    for (int n = 0; n < 4; n++)
      bfr[n] = *reinterpret_cast<const s16x8*>(&Bs[(wcol + n * 16 + lr) * BK + lg * 8]);
#pragma unroll
    for (int m = 0; m < MFR; m++)
#pragma unroll
      for (int n = 0; n < 4; n++)
        acc[m][n] = __builtin_amdgcn_mfma_f32_16x16x32_bf16(af[m], bfr[n], acc[m][n], 0, 0, 0);
    __syncthreads();
  }
#pragma unroll
  for (int m = 0; m < MFR; m++)
#pragma unroll
    for (int n = 0; n < 4; n++)
#pragma unroll
      for (int r = 0; r < 4; r++) {
        int row = rblk + wrow + m * 16 + lg * 4 + r;
        int col = cblk + wcol + n * 16 + lr;
        float val = acc[m][n][r];
        if constexpr (BF16OUT) ((short*)Cv)[(size_t)row * N + col] = f2bf(val);
        else                   ((float*)Cv)[(size_t)row * N + col] = val;
      }
}

// proj (bf16, [B][T][3][H][D]) -> RoPE -> Qb/Kb ([B][H][T][D]) and Vt ([B][H][D][T])
// block: 256 thr, handles (bh, 64 t-rows). V transposed through padded LDS tile.
__global__ __launch_bounds__(256) void rope_v2(const short* __restrict__ proj,
                                               short* __restrict__ Qb,
                                               short* __restrict__ Kb,
                                               short* __restrict__ Vt) {
  int tid = threadIdx.x;
  int t0 = blockIdx.x * 64;
  int bh = blockIdx.y;
  int b = bh >> 4, h = bh & 15;
  __shared__ short vtile[64 * 66];  // stride 66: <=2-way bank aliasing on both sides
  int i = tid & 31;
  int trow = tid >> 5;
  float freq = __expf(-(float)i * 0.2878231366f);  // ln(10000)/32
#pragma unroll
  for (int it = 0; it < 8; ++it) {
    int tl = it * 8 + trow;
    int t = t0 + tl;
    int pbase = (b * TT + t) * 3 * EMB + h * HD + 2 * i;
    unsigned q01 = *reinterpret_cast<const unsigned*>(proj + pbase);
    unsigned k01 = *reinterpret_cast<const unsigned*>(proj + pbase + EMB);
    unsigned v01 = *reinterpret_cast<const unsigned*>(proj + pbase + 2 * EMB);
    float qa = bf2f((unsigned short)(q01 & 0xffff)), qb_ = bf2f((unsigned short)(q01 >> 16));
    float ka = bf2f((unsigned short)(k01 & 0xffff)), kb_ = bf2f((unsigned short)(k01 >> 16));
    float ang = (float)t * freq;
    float s, c;
    sincosf(ang, &s, &c);
    int obase = (bh * TT + t) * HD + 2 * i;
    unsigned qo = ((unsigned)(unsigned short)f2bf(qa * s + qb_ * c) << 16) |
                  (unsigned short)f2bf(qa * c - qb_ * s);
    unsigned ko = ((unsigned)(unsigned short)f2bf(ka * s + kb_ * c) << 16) |
                  (unsigned short)f2bf(ka * c - kb_ * s);
    *reinterpret_cast<unsigned*>(Qb + obase) = qo;
    *reinterpret_cast<unsigned*>(Kb + obase) = ko;
    *reinterpret_cast<unsigned*>(&vtile[tl * 66 + 2 * i]) = v01;
  }
  __syncthreads();
  int d = tid >> 2, toff = (tid & 3) * 16;
  s16x8 o0, o1;
#pragma unroll
  for (int j = 0; j < 8; ++j) {
    o0[j] = vtile[(toff + j) * 66 + d];
    o1[j] = vtile[(toff + 8 + j) * 66 + d];
  }
  size_t vb = (size_t)(bh * HD + d) * TT + t0 + toff;
  *reinterpret_cast<s16x8*>(Vt + vb) = o0;
  *reinterpret_cast<s16x8*>(Vt + vb + 8) = o1;
}

// one wave per (bh, 16-query-row tile). Flash-style over 32-key tiles.
// V read from Vt [D][T]: PV B-fragment is one contiguous s16x8 per n.
__global__ __launch_bounds__(64) void attn_v2(const short* __restrict__ Qb,
                                              const short* __restrict__ Kb,
                                              const short* __restrict__ Vt,
                                              short* __restrict__ Xout) {
  const float NEG = -3.0e38f;
  int lane = threadIdx.x;
  int lr = lane & 15, lg = lane >> 4;
  int t0 = blockIdx.x * 16;
  int bh = blockIdx.y;
  int b = bh >> 4, h = bh & 15;
  const short* Qp = Qb + bh * TT * HD;
  const short* Kp = Kb + bh * TT * HD;
  const short* Vtp = Vt + bh * HD * TT;
  s16x8 qf[2];
#pragma unroll
  for (int d2 = 0; d2 < 2; d2++)
    qf[d2] = *reinterpret_cast<const s16x8*>(Qp + (t0 + lr) * HD + d2 * 32 + lg * 8);
  f32x4 of[4] = {};
  float m_run[4], l_run[4];
#pragma unroll
  for (int r = 0; r < 4; r++) { m_run[r] = NEG; l_run[r] = 0.0f; }
  __shared__ __align__(16) short p_lds[16][40];
  int lo = t0 - (CTX - 1); if (lo < 0) lo = 0;
  int kt_lo = lo & ~31;
  int kt_hi = (t0 + 15) & ~31;  // kt_hi+31 <= 2047 always: no clamps needed
  for (int kt = kt_lo; kt <= kt_hi; kt += 32) {
    f32x4 s2[2];
#pragma unroll
    for (int hh = 0; hh < 2; hh++) {
      int key = kt + hh * 16 + lr;
      f32x4 sa = {};
#pragma unroll
      for (int d2 = 0; d2 < 2; d2++) {
        s16x8 kf = *reinterpret_cast<const s16x8*>(Kp + key * HD + d2 * 32 + lg * 8);
        sa = __builtin_amdgcn_mfma_f32_16x16x32_bf16(qf[d2], kf, sa, 0, 0, 0);
      }
      s2[hh] = sa;
    }
#pragma unroll
    for (int r = 0; r < 4; r++) {
      int row = t0 + lg * 4 + r;
      float sv[2]; bool vd[2];
#pragma unroll
      for (int hh = 0; hh < 2; hh++) {
        int col = kt + hh * 16 + lr;
        int dl = row - col;
        vd[hh] = (dl >= 0) && (dl < CTX);
        sv[hh] = vd[hh] ? s2[hh][r] * 0.125f : NEG;
      }
      float mx = fmaxf(sv[0], sv[1]);
#pragma unroll
      for (int off = 1; off < 16; off <<= 1) mx = fmaxf(mx, __shfl_xor(mx, off, 16));
      float mnew = fmaxf(m_run[r], mx);
      float corr = __expf(m_run[r] - mnew);
      float psum = 0.0f;
#pragma unroll
      for (int hh = 0; hh < 2; hh++) {
        float p = vd[hh] ? __expf(sv[hh] - mnew) : 0.0f;
        p_lds[lg * 4 + r][hh * 16 + lr] = f2bf(p);
        psum += p;
      }
#pragma unroll
      for (int off = 1; off < 16; off <<= 1) psum += __shfl_xor(psum, off, 16);
      l_run[r] = l_run[r] * corr + psum;
      m_run[r] = mnew;
#pragma unroll
      for (int n = 0; n < 4; n++) of[n][r] *= corr;
    }
    __syncthreads();
    s16x8 pa = *reinterpret_cast<const s16x8*>(&p_lds[lr][lg * 8]);
#pragma unroll
    for (int n = 0; n < 4; n++) {
      s16x8 vf = *reinterpret_cast<const s16x8*>(Vtp + (size_t)(n * 16 + lr) * TT + kt + lg * 8);
      of[n] = __builtin_amdgcn_mfma_f32_16x16x32_bf16(pa, vf, of[n], 0, 0, 0);
    }
    __syncthreads();
  }
#pragma unroll
  for (int r = 0; r < 4; r++) {
    float inv = 1.0f / l_run[r];
    int row = t0 + lg * 4 + r;
#pragma unroll
    for (int n = 0; n < 4; n++)
      Xout[(b * TT + row) * EMB + h * HD + n * 16 + lr] = f2bf(of[n][r] * inv);
  }
}

extern "C" void kernel_launch(void* const* d_in, const int* in_sizes, int n_in,
                              void* d_out, int out_size, void* d_ws, size_t ws_size,
                              hipStream_t stream) {
  const float* query = (const float*)d_in[0];
  const float* w_in  = (const float*)d_in[1];
  const float* w_out = (const float*)d_in[2];
  char* ws = (char*)d_ws;
  short* qbf   = (short*)(ws + 0);          //  8388608  query bf16 [4096][1024]
  short* wibf  = (short*)(ws + 8388608);    //  6291456  in_proj bf16 [3072][1024]
  short* wobf  = (short*)(ws + 14680064);   //  2097152  out_proj bf16 [1024][1024]
  short* proj  = (short*)(ws + 16777216);   // 25165824  qkv proj bf16 [4096][3072]
  short* attnx = (short*)(ws + 16777216);   // alias: proj dead after rope
  short* Qb    = (short*)(ws + 41943040);   //  8388608  [B][H][T][D]
  short* Kb    = (short*)(ws + 50331648);   //  8388608  [B][H][T][D]
  short* Vt    = (short*)(ws + 58720256);   //  8388608  [B][H][D][T]

  cvt_bf16x4<<<4096, 256, 0, stream>>>(query, qbf, 1048576);
  cvt_bf16x4<<<3072, 256, 0, stream>>>(w_in, wibf, 786432);
  cvt_bf16x4<<<1024, 256, 0, stream>>>(w_out, wobf, 262144);
  gemm_lds<128, true><<<dim3(24, 32), 256, 0, stream>>>(qbf, wibf, (void*)proj, 3072, 1024);
  rope_v2<<<dim3(32, 32), 256, 0, stream>>>(proj, Qb, Kb, Vt);
  attn_v2<<<dim3(128, 32), 64, 0, stream>>>(Qb, Kb, Vt, attnx);
  gemm_lds<64, false><<<dim3(8, 64), 256, 0, stream>>>(attnx, wobf, d_out, 1024, 1024);
}

// Round 4
// 113.134 us; speedup vs baseline: 1.2732x; 1.2732x over previous
//
#include <hip/hip_runtime.h>

#define TT 2048
#define EMB 1024
#define NH 16
#define HD 64
#define CTX 250

typedef __attribute__((ext_vector_type(4))) float f32x4;
typedef __attribute__((ext_vector_type(8))) short s16x8;
typedef __attribute__((ext_vector_type(4))) short s16x4;

#define LDS_PTR(p) ((__attribute__((address_space(3))) void*)(p))
#define GLB_PTR(p) ((const __attribute__((address_space(1))) void*)(p))

__device__ __forceinline__ short f2bf(float f) {
  union { float f; unsigned u; } v; v.f = f;
  unsigned r = v.u + 0x7fffu + ((v.u >> 16) & 1u);
  return (short)(r >> 16);
}
__device__ __forceinline__ float bf2f(unsigned short u) {
  union { unsigned u; float f; } v; v.u = ((unsigned)u) << 16;
  return v.f;
}

__global__ void cvt_bf16x4(const float* __restrict__ in, short* __restrict__ out, int n4) {
  int i = blockIdx.x * blockDim.x + threadIdx.x;
  if (i >= n4) return;
  float4 v = reinterpret_cast<const float4*>(in)[i];
  s16x4 o; o[0] = f2bf(v.x); o[1] = f2bf(v.y); o[2] = f2bf(v.z); o[3] = f2bf(v.w);
  *reinterpret_cast<s16x4*>(out + i * 4) = o;
}

// C[M][N] = A[M][K] * W[N][K]^T  (bf16, MFMA 16x16x32, f32 accum)
template<int BM, bool BF16OUT>
__global__ __launch_bounds__(256) void gemm_lds(const short* __restrict__ A,
                                                const short* __restrict__ W,
                                                void* __restrict__ Cv, int N, int K) {
  constexpr int BN = 128;
  constexpr int BK = 32;
  constexpr int MFR = BM / 32;
  __shared__ __align__(16) short As[BM * BK];
  __shared__ __align__(16) short Bs[BN * BK];
  const int lane = threadIdx.x & 63;
  const int wid  = threadIdx.x >> 6;
  const int lr = lane & 15, lg = lane >> 4;
  const int rblk = blockIdx.y * BM;
  const int cblk = blockIdx.x * BN;
  const int wrow = (wid >> 1) * (BM / 2);
  const int wcol = (wid & 1) * 64;
  const int srow = lane >> 2;
  const int scol = (lane & 3) * 8;
  f32x4 acc[MFR][4] = {};

  for (int kk = 0; kk < K; kk += BK) {
#pragma unroll
    for (int j = 0; j < BM / 64; j++) {
      int seg = wid * (BM / 64) + j;
      const short* g = A + (size_t)(rblk + seg * 16 + srow) * K + kk + scol;
      __builtin_amdgcn_global_load_lds(GLB_PTR(g), LDS_PTR(&As[seg * 512]), 16, 0, 0);
    }
#pragma unroll
    for (int j = 0; j < 2; j++) {
      int seg = wid * 2 + j;
      const short* g = W + (size_t)(cblk + seg * 16 + srow) * K + kk + scol;
      __builtin_amdgcn_global_load_lds(GLB_PTR(g), LDS_PTR(&Bs[seg * 512]), 16, 0, 0);
    }
    __syncthreads();
    s16x8 af[MFR], bfr[4];
#pragma unroll
    for (int m = 0; m < MFR; m++)
      af[m] = *reinterpret_cast<const s16x8*>(&As[(wrow + m * 16 + lr) * BK + lg * 8]);
#pragma unroll
    for (int n = 0; n < 4; n++)
      bfr[n] = *reinterpret_cast<const s16x8*>(&Bs[(wcol + n * 16 + lr) * BK + lg * 8]);
#pragma unroll
    for (int m = 0; m < MFR; m++)
#pragma unroll
      for (int n = 0; n < 4; n++)
        acc[m][n] = __builtin_amdgcn_mfma_f32_16x16x32_bf16(af[m], bfr[n], acc[m][n], 0, 0, 0);
    __syncthreads();
  }
#pragma unroll
  for (int m = 0; m < MFR; m++)
#pragma unroll
    for (int n = 0; n < 4; n++)
#pragma unroll
      for (int r = 0; r < 4; r++) {
        int row = rblk + wrow + m * 16 + lg * 4 + r;
        int col = cblk + wcol + n * 16 + lr;
        float val = acc[m][n][r];
        if constexpr (BF16OUT) ((short*)Cv)[(size_t)row * N + col] = f2bf(val);
        else                   ((float*)Cv)[(size_t)row * N + col] = val;
      }
}

// proj (bf16, [B][T][3][H][D]) -> RoPE -> Qb/Kb ([B][H][T][D]) and Vt ([B][H][D][T])
__global__ __launch_bounds__(256) void rope_v2(const short* __restrict__ proj,
                                               short* __restrict__ Qb,
                                               short* __restrict__ Kb,
                                               short* __restrict__ Vt) {
  int tid = threadIdx.x;
  int t0 = blockIdx.x * 64;
  int bh = blockIdx.y;
  int b = bh >> 4, h = bh & 15;
  __shared__ short vtile[64 * 66];
  int i = tid & 31;
  int trow = tid >> 5;
  float freq = __expf(-(float)i * 0.2878231366f);  // ln(10000)/32
#pragma unroll
  for (int it = 0; it < 8; ++it) {
    int tl = it * 8 + trow;
    int t = t0 + tl;
    int pbase = (b * TT + t) * 3 * EMB + h * HD + 2 * i;
    unsigned q01 = *reinterpret_cast<const unsigned*>(proj + pbase);
    unsigned k01 = *reinterpret_cast<const unsigned*>(proj + pbase + EMB);
    unsigned v01 = *reinterpret_cast<const unsigned*>(proj + pbase + 2 * EMB);
    float qa = bf2f((unsigned short)(q01 & 0xffff)), qb_ = bf2f((unsigned short)(q01 >> 16));
    float ka = bf2f((unsigned short)(k01 & 0xffff)), kb_ = bf2f((unsigned short)(k01 >> 16));
    float ang = (float)t * freq;
    float s, c;
    sincosf(ang, &s, &c);
    int obase = (bh * TT + t) * HD + 2 * i;
    unsigned qo = ((unsigned)(unsigned short)f2bf(qa * s + qb_ * c) << 16) |
                  (unsigned short)f2bf(qa * c - qb_ * s);
    unsigned ko = ((unsigned)(unsigned short)f2bf(ka * s + kb_ * c) << 16) |
                  (unsigned short)f2bf(ka * c - kb_ * s);
    *reinterpret_cast<unsigned*>(Qb + obase) = qo;
    *reinterpret_cast<unsigned*>(Kb + obase) = ko;
    *reinterpret_cast<unsigned*>(&vtile[tl * 66 + 2 * i]) = v01;
  }
  __syncthreads();
  int d = tid >> 2, toff = (tid & 3) * 16;
  s16x8 o0, o1;
#pragma unroll
  for (int j = 0; j < 8; ++j) {
    o0[j] = vtile[(toff + j) * 66 + d];
    o1[j] = vtile[(toff + 8 + j) * 66 + d];
  }
  size_t vb = (size_t)(bh * HD + d) * TT + t0 + toff;
  *reinterpret_cast<s16x8*>(Vt + vb) = o0;
  *reinterpret_cast<s16x8*>(Vt + vb + 8) = o1;
}

// 4-wave blocks: 64 q-rows/block, K/V tiles staged once per block into
// swizzled LDS (linear dest + inverse-swizzled global src + swizzled reads).
// XCD-chunked block mapping: 8 XCDs x 4 bh x 32 t-blocks.
__global__ __launch_bounds__(256) void attn_v3(const short* __restrict__ Qb,
                                               const short* __restrict__ Kb,
                                               const short* __restrict__ Vt,
                                               short* __restrict__ Xout) {
  const float NEG = -3.0e38f;
  int tid = threadIdx.x;
  int lane = tid & 63;
  int w = tid >> 6;
  int lr = lane & 15, lg = lane >> 4;
  int id = blockIdx.x;
  int xcd = id & 7;
  int sub = id >> 3;                 // 0..127
  int bh = xcd * 4 + (sub >> 5);     // 4 bh per XCD
  int tblk = (sub & 31) * 64;
  int t0 = tblk + w * 16;
  int b = bh >> 4, h = bh & 15;
  const short* Qp = Qb + bh * TT * HD;
  const char* Kp = (const char*)(Kb + bh * TT * HD);   // rows of 128B
  const char* Vtp = (const char*)(Vt + bh * HD * TT);  // rows of 4096B
  __shared__ __align__(16) short Ks[32 * 64];   // [32 keys][128B], XOR-swizzled
  __shared__ __align__(16) short Vs[64 * 32];   // [64 d][64B], XOR-swizzled
  __shared__ __align__(16) short p_lds[4][16][40];
  s16x8 qf[2];
#pragma unroll
  for (int d2 = 0; d2 < 2; d2++)
    qf[d2] = *reinterpret_cast<const s16x8*>(Qp + (t0 + lr) * HD + d2 * 32 + lg * 8);
  f32x4 of[4] = {};
  float m_run[4], l_run[4];
#pragma unroll
  for (int r = 0; r < 4; r++) { m_run[r] = NEG; l_run[r] = 0.0f; }
  int lo = tblk - (CTX - 1); if (lo < 0) lo = 0;
  int kt_lo = lo & ~31;
  int kt_hi = (tblk + 63) & ~31;
  // staging addresses (loop-invariant parts)
  int krow = w * 8 + (lane >> 3);              // key-row staged by this lane
  int kcb  = ((lane & 7) * 16) ^ ((krow & 7) << 4);
  int vd   = w * 16 + (lane >> 2);             // d-row staged by this lane
  int vcb  = ((lane & 3) * 16) ^ (((vd >> 1) & 3) << 4);
  char* ksdst = (char*)Ks + w * 1024 + lane * 16;
  char* vsdst = (char*)Vs + w * 1024 + lane * 16;
  for (int kt = kt_lo; kt <= kt_hi; kt += 32) {
    __builtin_amdgcn_global_load_lds(GLB_PTR(Kp + (kt + krow) * 128 + kcb),
                                     LDS_PTR(ksdst), 16, 0, 0);
    __builtin_amdgcn_global_load_lds(GLB_PTR(Vtp + vd * (TT * 2) + kt * 2 + vcb),
                                     LDS_PTR(vsdst), 16, 0, 0);
    __syncthreads();
    // wave-uniform skip: tile fully outside this wave's window?
    if (kt <= t0 + 15 && kt + 31 >= t0 - (CTX - 1)) {
      f32x4 s2[2];
#pragma unroll
      for (int hh = 0; hh < 2; hh++) {
        int row = hh * 16 + lr;
        f32x4 sa = {};
#pragma unroll
        for (int d2 = 0; d2 < 2; d2++) {
          int cb = (d2 * 64 + lg * 16) ^ ((row & 7) << 4);
          s16x8 kf = *reinterpret_cast<const s16x8*>((const char*)Ks + row * 128 + cb);
          sa = __builtin_amdgcn_mfma_f32_16x16x32_bf16(qf[d2], kf, sa, 0, 0, 0);
        }
        s2[hh] = sa;
      }
#pragma unroll
      for (int r = 0; r < 4; r++) {
        int row = t0 + lg * 4 + r;
        float sv[2]; bool vdm[2];
#pragma unroll
        for (int hh = 0; hh < 2; hh++) {
          int col = kt + hh * 16 + lr;
          int dl = row - col;
          vdm[hh] = (dl >= 0) && (dl < CTX);
          sv[hh] = vdm[hh] ? s2[hh][r] * 0.125f : NEG;
        }
        float mx = fmaxf(sv[0], sv[1]);
#pragma unroll
        for (int off = 1; off < 16; off <<= 1) mx = fmaxf(mx, __shfl_xor(mx, off, 16));
        float mnew = fmaxf(m_run[r], mx);
        float corr = __expf(m_run[r] - mnew);
        float psum = 0.0f;
#pragma unroll
        for (int hh = 0; hh < 2; hh++) {
          float p = vdm[hh] ? __expf(sv[hh] - mnew) : 0.0f;
          p_lds[w][lg * 4 + r][hh * 16 + lr] = f2bf(p);
          psum += p;
        }
#pragma unroll
        for (int off = 1; off < 16; off <<= 1) psum += __shfl_xor(psum, off, 16);
        l_run[r] = l_run[r] * corr + psum;
        m_run[r] = mnew;
#pragma unroll
        for (int n = 0; n < 4; n++) of[n][r] *= corr;
      }
      s16x8 pa = *reinterpret_cast<const s16x8*>(&p_lds[w][lr][lg * 8]);
#pragma unroll
      for (int n = 0; n < 4; n++) {
        int d = n * 16 + lr;
        int cb = (lg * 16) ^ (((d >> 1) & 3) << 4);
        s16x8 vf = *reinterpret_cast<const s16x8*>((const char*)Vs + d * 64 + cb);
        of[n] = __builtin_amdgcn_mfma_f32_16x16x32_bf16(pa, vf, of[n], 0, 0, 0);
      }
    }
    __syncthreads();
  }
#pragma unroll
  for (int r = 0; r < 4; r++) {
    float inv = 1.0f / l_run[r];
    int row = t0 + lg * 4 + r;
#pragma unroll
    for (int n = 0; n < 4; n++)
      Xout[(b * TT + row) * EMB + h * HD + n * 16 + lr] = f2bf(of[n][r] * inv);
  }
}

extern "C" void kernel_launch(void* const* d_in, const int* in_sizes, int n_in,
                              void* d_out, int out_size, void* d_ws, size_t ws_size,
                              hipStream_t stream) {
  const float* query = (const float*)d_in[0];
  const float* w_in  = (const float*)d_in[1];
  const float* w_out = (const float*)d_in[2];
  char* ws = (char*)d_ws;
  short* qbf   = (short*)(ws + 0);          //  8388608  query bf16 [4096][1024]
  short* wibf  = (short*)(ws + 8388608);    //  6291456  in_proj bf16 [3072][1024]
  short* wobf  = (short*)(ws + 14680064);   //  2097152  out_proj bf16 [1024][1024]
  short* proj  = (short*)(ws + 16777216);   // 25165824  qkv proj bf16 [4096][3072]
  short* attnx = (short*)(ws + 16777216);   // alias: proj dead after rope
  short* Qb    = (short*)(ws + 41943040);   //  8388608  [B][H][T][D]
  short* Kb    = (short*)(ws + 50331648);   //  8388608  [B][H][T][D]
  short* Vt    = (short*)(ws + 58720256);   //  8388608  [B][H][D][T]

  cvt_bf16x4<<<4096, 256, 0, stream>>>(query, qbf, 1048576);
  cvt_bf16x4<<<3072, 256, 0, stream>>>(w_in, wibf, 786432);
  cvt_bf16x4<<<1024, 256, 0, stream>>>(w_out, wobf, 262144);
  gemm_lds<128, true><<<dim3(24, 32), 256, 0, stream>>>(qbf, wibf, (void*)proj, 3072, 1024);
  rope_v2<<<dim3(32, 32), 256, 0, stream>>>(proj, Qb, Kb, Vt);
  attn_v3<<<1024, 256, 0, stream>>>(Qb, Kb, Vt, attnx);
  gemm_lds<64, false><<<dim3(8, 64), 256, 0, stream>>>(attnx, wobf, d_out, 1024, 1024);
}